// Round 1
// baseline (242.547 us; speedup 1.0000x reference)
//
#include <hip/hip_runtime.h>
#include <math.h>

// LogHarmonicLowering: out[b, k*C+c, f, t] = lerp-gather of x[b, c, f + 200*ln(k+1), t]
// with zero padding outside [0, F). Memory-bound: 671MB out + 134MB in.

#define BATCH 4
#define CH    16
#define KK    5
#define FREQ  1024
#define TT    512
#define T4    (TT / 4)   // 128 float4 per row

__global__ __launch_bounds__(256) void lhl_kernel(const float* __restrict__ x,
                                                  float* __restrict__ out,
                                                  int total4) {
    __shared__ float sh[KK];
    if (threadIdx.x < KK) {
        // matches numpy: shifts[k] = -(200*ln(0.001*(k+1)) - 200*ln(0.001)) = -200*ln(k+1)
        // pos = f - shifts[k] = f + 200*ln(k+1); double precision then round to f32.
        sh[threadIdx.x] = (float)(200.0 * log((double)(threadIdx.x + 1)));
    }
    __syncthreads();

    const float4* __restrict__ xin = (const float4*)x;
    float4* __restrict__ o4 = (float4*)out;

    int stride = (int)(gridDim.x * blockDim.x);
    for (int idx = (int)(blockIdx.x * blockDim.x + threadIdx.x); idx < total4; idx += stride) {
        int t4 = idx & (T4 - 1);
        int row = idx >> 7;           // / T4
        int f = row & (FREQ - 1);
        int rc = row >> 10;           // / FREQ
        int c = rc & (CH - 1);
        int bk = rc >> 4;             // / CH  -> b*KK + k, range [0, BATCH*KK)
        int k = bk % KK;
        int b = bk / KK;

        float pos = (float)f + sh[k];
        float fi0 = floorf(pos);
        int i0 = (int)fi0;
        float w = pos - fi0;

        float w0 = (i0 >= 0 && i0 < FREQ) ? (1.0f - w) : 0.0f;
        float w1 = (i0 + 1 >= 0 && i0 + 1 < FREQ) ? w : 0.0f;
        int i0c = min(max(i0, 0), FREQ - 1);
        int i1c = min(max(i0 + 1, 0), FREQ - 1);

        long long base = ((long long)(b * CH + c) * FREQ) * T4;
        float4 g0 = xin[base + (long long)i0c * T4 + t4];
        float4 g1 = xin[base + (long long)i1c * T4 + t4];

        float4 r;
        r.x = g0.x * w0 + g1.x * w1;
        r.y = g0.y * w0 + g1.y * w1;
        r.z = g0.z * w0 + g1.z * w1;
        r.w = g0.w * w0 + g1.w * w1;
        o4[idx] = r;
    }
}

extern "C" void kernel_launch(void* const* d_in, const int* in_sizes, int n_in,
                              void* d_out, int out_size, void* d_ws, size_t ws_size,
                              hipStream_t stream) {
    const float* x = (const float*)d_in[0];
    float* out = (float*)d_out;
    int total4 = BATCH * KK * CH * FREQ * T4;   // 41,943,040
    int block = 256;
    int grid = 4096;                            // grid-stride, ~80 iters/thread
    lhl_kernel<<<grid, block, 0, stream>>>(x, out, total4);
}

// Round 3
// 201.993 us; speedup vs baseline: 1.2008x; 1.2008x over previous
//
#include <hip/hip_runtime.h>
#include <math.h>

// LogHarmonicLowering: out[b, k*C+c, f, t] = lerp-gather of x[b, c, f + 200*ln(k+1), t]
// with zero padding outside [0, F). Memory-bound: ideal 671MB out + 134MB in.
// R3: non-temporal output stores (via native ext_vector_type, since the builtin
// rejects HIP_vector_type float4) so the 671MB output stream doesn't evict the
// L3-resident input (re-read by all 5 k-blocks).

#define BATCH 4
#define CH    16
#define KK    5
#define FREQ  1024
#define TT    512
#define T4    (TT / 4)   // 128 float4 per row

typedef float f32x4 __attribute__((ext_vector_type(4)));

__global__ __launch_bounds__(256) void lhl_kernel(const float* __restrict__ x,
                                                  float* __restrict__ out,
                                                  int total4) {
    __shared__ float sh[KK];
    if (threadIdx.x < KK) {
        // shifts[k] = -(200*ln(0.001*(k+1)) - 200*ln(0.001)) = -200*ln(k+1)
        // pos = f - shifts[k] = f + 200*ln(k+1); double precision then round to f32.
        sh[threadIdx.x] = (float)(200.0 * log((double)(threadIdx.x + 1)));
    }
    __syncthreads();

    const f32x4* __restrict__ xin = (const f32x4*)x;
    f32x4* __restrict__ o4 = (f32x4*)out;

    int stride = (int)(gridDim.x * blockDim.x);
    for (int idx = (int)(blockIdx.x * blockDim.x + threadIdx.x); idx < total4; idx += stride) {
        int t4 = idx & (T4 - 1);
        int row = idx >> 7;           // / T4
        int f = row & (FREQ - 1);
        int rc = row >> 10;           // / FREQ
        int c = rc & (CH - 1);
        int bk = rc >> 4;             // / CH  -> b*KK + k, range [0, BATCH*KK)
        int k = bk % KK;
        int b = bk / KK;

        float pos = (float)f + sh[k];
        float fi0 = floorf(pos);
        int i0 = (int)fi0;
        float w = pos - fi0;

        float w0 = (i0 >= 0 && i0 < FREQ) ? (1.0f - w) : 0.0f;
        float w1 = (i0 + 1 >= 0 && i0 + 1 < FREQ) ? w : 0.0f;
        int i0c = min(max(i0, 0), FREQ - 1);
        int i1c = min(max(i0 + 1, 0), FREQ - 1);

        long long base = ((long long)(b * CH + c) * FREQ) * T4;
        f32x4 g0 = xin[base + (long long)i0c * T4 + t4];
        f32x4 g1 = xin[base + (long long)i1c * T4 + t4];

        f32x4 r = g0 * w0 + g1 * w1;
        __builtin_nontemporal_store(r, &o4[idx]);
    }
}

extern "C" void kernel_launch(void* const* d_in, const int* in_sizes, int n_in,
                              void* d_out, int out_size, void* d_ws, size_t ws_size,
                              hipStream_t stream) {
    const float* x = (const float*)d_in[0];
    float* out = (float*)d_out;
    int total4 = BATCH * KK * CH * FREQ * T4;   // 41,943,040
    int block = 256;
    int grid = 4096;                            // grid-stride, 40 iters/thread
    lhl_kernel<<<grid, block, 0, stream>>>(x, out, total4);
}

// Round 4
// 145.509 us; speedup vs baseline: 1.6669x; 1.3882x over previous
//
#include <hip/hip_runtime.h>
#include <math.h>

// LogHarmonicLowering: out[b, k*C+c, f, t] = lerp-gather of x[b, c, f + 200*ln(k+1), t]
// zero-padded above F. Ideal traffic: 134MB read + 671MB write.
// R4: XCD-L2-locality schedule. Each XCD group (blockIdx%8, 256 blocks) walks
// the 8 (b,c) slices assigned to it one at a time, covering ALL 5 k for that
// slice concurrently -> the 2MB input slice is fetched once into the XCD's
// 4MB L2 and re-read 5x from L2. NT stores keep the 671MB output stream from
// polluting the caches.

#define BATCH 4
#define CH    16
#define KK    5
#define FREQ  1024
#define T4    128                 // 512 floats = 128 float4 per row
#define SLICE_F4 (FREQ * T4)      // 131072 = 1<<17, per (b,c) or per (b,k,c) plane
#define NSLICE (BATCH * CH)       // 64 input slices
#define BLOCKS_PER_XCD 256
#define SLICES_PER_XCD (NSLICE / 8)            // 8
#define F4_PER_SLICE (KK * SLICE_F4)           // 655360
#define F4_PER_BLOCK (F4_PER_SLICE / BLOCKS_PER_XCD)  // 2560
#define ITERS (F4_PER_BLOCK / 256)             // 10

typedef float f32x4 __attribute__((ext_vector_type(4)));

__global__ __launch_bounds__(256) void lhl_kernel(const float* __restrict__ x,
                                                  float* __restrict__ out) {
    __shared__ float sh[KK];
    if (threadIdx.x < KK) {
        // shift[k] = 200*ln(k+1); pos = f + shift[k]. f64 then round to f32.
        sh[threadIdx.x] = (float)(200.0 * log((double)(threadIdx.x + 1)));
    }
    __syncthreads();

    const f32x4* __restrict__ xin = (const f32x4*)x;
    f32x4* __restrict__ o4 = (f32x4*)out;

    int xcd = blockIdx.x & 7;        // round-robin XCD assignment (m09)
    int lid = blockIdx.x >> 3;       // 0..255 within group
    int ebase = lid * F4_PER_BLOCK;

    for (int si = 0; si < SLICES_PER_XCD; ++si) {
        int slice = xcd * SLICES_PER_XCD + si;   // (b,c) slice id
        int b = slice >> 4;
        int c = slice & (CH - 1);
        long long ibase = (long long)slice << 17;      // input plane base (f4)

        #pragma unroll
        for (int it = 0; it < ITERS; ++it) {
            int e = ebase + it * 256 + (int)threadIdx.x;   // [0, 655360)
            int k = e >> 17;                  // per-k plane = 1<<17 f4
            int rem = e & (SLICE_F4 - 1);     // f*128 + t4
            int f = rem >> 7;
            int t4 = rem & (T4 - 1);

            float pos = (float)f + sh[k];
            float fi0 = floorf(pos);
            int i0 = (int)fi0;                // pos >= 0 always (shifts >= 0)
            float w = pos - fi0;

            float w0 = (i0 < FREQ) ? (1.0f - w) : 0.0f;
            float w1 = (i0 + 1 < FREQ) ? w : 0.0f;
            int i0c = min(i0, FREQ - 1);
            int i1c = min(i0 + 1, FREQ - 1);

            f32x4 g0 = xin[ibase + i0c * T4 + t4];
            f32x4 g1 = xin[ibase + i1c * T4 + t4];
            f32x4 r = g0 * w0 + g1 * w1;

            long long oidx = ((long long)(b * (KK * CH) + k * CH + c) << 17) + rem;
            __builtin_nontemporal_store(r, &o4[oidx]);
        }
    }
}

extern "C" void kernel_launch(void* const* d_in, const int* in_sizes, int n_in,
                              void* d_out, int out_size, void* d_ws, size_t ws_size,
                              hipStream_t stream) {
    const float* x = (const float*)d_in[0];
    float* out = (float*)d_out;
    lhl_kernel<<<8 * BLOCKS_PER_XCD, 256, 0, stream>>>(x, out);
}

// Round 5
// 142.575 us; speedup vs baseline: 1.7012x; 1.0206x over previous
//
#include <hip/hip_runtime.h>
#include <math.h>

// LogHarmonicLowering: out[b, k*C+c, f, t] = lerp of x[b, c, floor(f+s_k)(+1), t],
// s_k = 200*ln(k+1); zero where floor(f+s_k) >= F. Ideal traffic 134MB R + 671MB W.
// R5: per-block LDS staging of a 17-row input window -> HBM fetch == 139MB by
// construction (no reliance on L2 retention / inter-block timing). Zero tail
// (i0>=F, 18.6% of output) written by a separate balanced zero pass (no reads).
// NT stores throughout.

#define CH   16
#define KK   5
#define FREQ 1024
#define T4   128   // 512 floats = 128 float4 per row

typedef float f32x4 __attribute__((ext_vector_type(4)));

// 200*ln(k+1) rounded f64->f32 exactly as numpy does
#define S1 ((float)138.62943611198906)
#define S2 ((float)219.72245773362196)
#define S3 ((float)277.2588722239781)
#define S4 ((float)321.88758248682006)

__device__ __forceinline__ int first_zero_f(float s) {
    // min f with floorf(f + s) >= FREQ, using the SAME f32 math as the main path
    int fz = (int)(1024.0f - s);
    while (fz > 0 && (int)floorf((float)(fz - 1) + s) >= FREQ) fz--;
    while ((int)floorf((float)fz + s) < FREQ) fz++;
    return fz;
}

__global__ __launch_bounds__(256) void lhl_kernel(const float* __restrict__ x,
                                                  float* __restrict__ out) {
    __shared__ float lds[17 * 512];   // 34816 B -> 4 blocks/CU
    const int tid = threadIdx.x;
    const int bi  = (int)blockIdx.x;
    const int j     = bi & 63;        // f-window: input rows [16j, 16j+nrows)
    const int slice = bi >> 6;        // b*16 + c
    const int b = slice >> 4, c = slice & 15;
    const int nrows = (j == 63) ? 16 : 17;
    const int nf4 = nrows << 7;
    const int j16 = j << 4;

    // ---- stage input window into LDS (linear, global_load_lds width 16) ----
    const float* src = x + ((size_t)slice << 19) + ((size_t)j << 13);
    for (int e = tid; e < nf4; e += 256) {
        __builtin_amdgcn_global_load_lds(
            (const __attribute__((address_space(1))) void*)(src + (e << 2)),
            (__attribute__((address_space(3))) void*)(lds + (e << 2)),
            16, 0, 0);
    }
    __syncthreads();

    f32x4* __restrict__ o4 = (f32x4*)out;

    // ---- main region: outputs whose i0 = floor(f+s_k) lies in this window ----
    #pragma unroll
    for (int k = 0; k < KK; ++k) {
        const float s = (k == 0) ? 0.0f : (k == 1) ? S1 : (k == 2) ? S2
                       : (k == 3) ? S3 : S4;
        const int fbase = (int)ceilf((float)j16 - s) - 1;   // 18-candidate scan, +-1 slack
        #pragma unroll
        for (int it = 0; it < 9; ++it) {
            int e = (it << 8) + tid;          // 0..2303 -> 18 rows x 128 f4
            int m = e >> 7, t4 = e & 127;
            int f = fbase + m;
            float pos = (float)f + s;
            int i0 = (int)floorf(pos);
            if (f >= 0 && (i0 >> 4) == j) {   // exact ownership partition; implies 0<=i0<FREQ
                float w = pos - (float)i0;
                int r = i0 - j16;             // 0..15
                float w1 = (i0 + 1 < FREQ) ? w : 0.0f;
                int r1 = min(r + 1, nrows - 1);   // row 16j+16 staged unless j==63 (then w1==0)
                f32x4 g0 = *(const f32x4*)&lds[(r  << 9) + (t4 << 2)];
                f32x4 g1 = *(const f32x4*)&lds[(r1 << 9) + (t4 << 2)];
                f32x4 res = g0 * (1.0f - w) + g1 * w1;
                size_t o = ((size_t)((b * KK + k) * CH + c) << 17) + ((size_t)f << 7) + t4;
                __builtin_nontemporal_store(res, o4 + o);
            }
        }
    }

    // ---- zero tail: i0 >= FREQ -> out = 0 (no reads). Balanced across the 64
    // j-blocks of this slice: each writes 2*Z f4 of the slice's 128*Z zero f4. ----
    const int fz1 = first_zero_f(S1), fz2 = first_zero_f(S2),
              fz3 = first_zero_f(S3), fz4 = first_zero_f(S4);
    const int n1 = FREQ - fz1, n2 = FREQ - fz2, n3 = FREQ - fz3, n4 = FREQ - fz4;
    const int cum1 = n1, cum2 = cum1 + n2, cum3 = cum2 + n3, Z = cum3 + n4;
    const int twoZ = Z << 1;
    const int zbase = twoZ * j;               // this block's offset in slice z-space
    const f32x4 zero = {0.f, 0.f, 0.f, 0.f};
    for (int l = tid; l < twoZ; l += 256) {
        int zz = zbase + l;
        int zrow = zz >> 7, t4 = zz & 127;
        int k, f;
        if (zrow < cum1)      { k = 1; f = fz1 + zrow; }
        else if (zrow < cum2) { k = 2; f = fz2 + (zrow - cum1); }
        else if (zrow < cum3) { k = 3; f = fz3 + (zrow - cum2); }
        else                  { k = 4; f = fz4 + (zrow - cum3); }
        size_t o = ((size_t)((b * KK + k) * CH + c) << 17) + ((size_t)f << 7) + t4;
        __builtin_nontemporal_store(zero, o4 + o);
    }
}

extern "C" void kernel_launch(void* const* d_in, const int* in_sizes, int n_in,
                              void* d_out, int out_size, void* d_ws, size_t ws_size,
                              hipStream_t stream) {
    const float* x = (const float*)d_in[0];
    float* out = (float*)d_out;
    lhl_kernel<<<64 * 64, 256, 0, stream>>>(x, out);   // 64 slices x 64 f-windows
}

// Round 6
// 136.988 us; speedup vs baseline: 1.7706x; 1.0408x over previous
//
#include <hip/hip_runtime.h>
#include <math.h>

// LogHarmonicLowering. Structural fact: f integer => floor(f + s_k) = f + D_k,
// D_k = floor(s_k) constant per k (s_k fracs are >=0.25 from integers; f32 ulp
// <=1.2e-4 can't cross). So out(k, f) = rows[f+D_k]*(1-w) + rows[f+D_k+1]*w1.
// R6: pure register pipeline. Each wave loads 17 input half-rows (f4/lane) to
// VGPRs and NT-stores the 80 dependent output half-rows. No LDS, no barriers,
// no block-wide vmcnt drains. Zero tail (i0 >= F) in a balanced no-read pass.

#define CH   16
#define KK   5
#define FREQ 1024
#define T4   128

typedef float f32x4 __attribute__((ext_vector_type(4)));

// f32(200*(ln(0.001*(k+1)) - ln(0.001))), matching numpy f64 then f32 cast
__device__ __constant__ const float S_TAB[5] = {
    0.0f, 138.62943611198906f, 219.72245773362196f, 277.2588722239781f, 321.88758248682006f
};
#define D0 0
#define D1 138
#define D2 219
#define D3 277
#define D4 321

__global__ __launch_bounds__(256) void lhl_kernel(const float* __restrict__ x,
                                                  float* __restrict__ out) {
    const int tid  = (int)threadIdx.x;
    const int wave = tid >> 6, lane = tid & 63;
    const int bi   = (int)blockIdx.x;

    // strip = one wave's task: (slice, j-window, half-row)
    const int strip = bi * 4 + wave;        // 0..8191
    const int half  = strip & 1;
    const int j     = (strip >> 1) & 63;    // input rows [16j, 16j+17)
    const int slice = strip >> 7;           // b*16 + c
    const int b = slice >> 4, c = slice & 15;
    const int a = j << 4;

    const f32x4* __restrict__ xin = (const f32x4*)x;
    f32x4* __restrict__ o4 = (f32x4*)out;

    const size_t sbase = (size_t)slice << 17;
    const int col = (half << 6) + lane;     // t4 in [0,128)

    // ---- load 17 half-rows into registers (j==63: dup row 15, unused w1=0) ----
    const int nload = (j == 63) ? 16 : 17;
    f32x4 rows[17];
    #pragma unroll
    for (int r = 0; r < 17; ++r) {
        int rr = min(r, nload - 1);
        rows[r] = xin[sbase + ((size_t)(a + rr) << 7) + col];
    }

    // ---- emit 5 outputs per row-pair as loads arrive ----
    const int dtab[5] = {D0, D1, D2, D3, D4};
    #pragma unroll
    for (int r = 0; r < 16; ++r) {
        const int i0 = a + r;
        #pragma unroll
        for (int k = 0; k < KK; ++k) {
            const int f = i0 - dtab[k];
            if (f >= 0) {                           // wave-uniform
                float pos = (float)f + S_TAB[k];
                float w = pos - floorf(pos);        // == frac, reference-exact f32
                float w1 = (i0 + 1 < FREQ) ? w : 0.0f;
                f32x4 res = rows[r] * (1.0f - w) + rows[r + 1] * w1;
                size_t o = ((size_t)((b * KK + k) * CH + c) << 17)
                         + ((size_t)f << 7) + col;
                __builtin_nontemporal_store(res, o4 + o);
            }
        }
    }

    // ---- zero tail: f in [1024-D_k, 1024), k=1..4 -> 955 rows/slice, split
    // over the 32 blocks of this slice (32*3820 = 955*128 f4 exactly) ----
    const int blkin = bi & 31;
    const f32x4 zero = {0.f, 0.f, 0.f, 0.f};
    for (int l = tid; l < 3820; l += 256) {
        int zz = blkin * 3820 + l;
        int zrow = zz >> 7, t4z = zz & 127;
        int k, f;
        if (zrow < 138)      { k = 1; f = (FREQ - D1) + zrow; }
        else if (zrow < 357) { k = 2; f = (FREQ - D2) + (zrow - 138); }
        else if (zrow < 634) { k = 3; f = (FREQ - D3) + (zrow - 357); }
        else                 { k = 4; f = (FREQ - D4) + (zrow - 634); }
        size_t o = ((size_t)((b * KK + k) * CH + c) << 17) + ((size_t)f << 7) + t4z;
        __builtin_nontemporal_store(zero, o4 + o);
    }
}

extern "C" void kernel_launch(void* const* d_in, const int* in_sizes, int n_in,
                              void* d_out, int out_size, void* d_ws, size_t ws_size,
                              hipStream_t stream) {
    const float* x = (const float*)d_in[0];
    float* out = (float*)d_out;
    lhl_kernel<<<2048, 256, 0, stream>>>(x, out);   // 8192 wave-strips
}